// Round 1
// baseline (98.937 us; speedup 1.0000x reference)
//
#include <hip/hip_runtime.h>

// WeightedTensorProduct: out[b, seg[k], c] += x1[b,M1[k],c]*x2[b,M2[k],c]*CG[k]*W[l_ind[k],c]
// Structure is a deterministic function of L=3 -> replicated at compile time.
// R7: amortize per-thread fixed costs over 2 channels (float2 per thread):
//   - 478 v_readlane cg broadcasts issued ONCE, feed both channels' FMAs
//   - global loads/stores become dwordx2 (halved VMEM instruction count)
//   - w reads become ds_read_b64 (halved DS count; lanes 0..15 cover all 32
//     banks exactly once -> conflict-free)
//   - <2 x float> math gives the backend the chance to form full-rate
//     v_pk_mul_f32 / v_pk_fma_f32 (gfx950 packed fp32)
//   - keeps the R6 invariants: NO s_load chain for cg (R1/R5 serialization),
//     ~90 VGPR so the 104/128-reg tier cannot spill (R3 scratch blowup)

#define LMAX 3
#define MOUT 16          // (L+1)^2
#define CCH 128          // channels
#define NTRI 34
#define NNZ 478
#define NPAIR 156        // nonempty (output-order, triple) pairs
#define NCGV 8           // ceil(NNZ/64) VGPRs holding cg per wave

typedef __attribute__((ext_vector_type(2))) float f2;

struct Tables {
    int n_tri = 0;
    int nnz = 0;
    int np = 0;
    int tl[NTRI] = {}, tl1[NTRI] = {}, tl2[NTRI] = {};
    int M1[NNZ] = {}, M2[NNZ] = {};
    int pair_tri[NPAIR] = {};
    int pair_kstart[NPAIR + 1] = {};
    int mo_pstart[MOUT + 1] = {};
};

constexpr Tables build_tables() {
    Tables T{};
    // triples, insertion order == tri_index order in the reference
    for (int l1 = 0; l1 <= LMAX; ++l1) {
        for (int l2 = 0; l2 <= LMAX; ++l2) {
            int lo = l1 - l2; if (lo < 0) lo = -lo;
            int hi = l1 + l2; if (hi > LMAX) hi = LMAX;
            for (int l = lo; l <= hi; ++l) {
                T.tl[T.n_tri] = l; T.tl1[T.n_tri] = l1; T.tl2[T.n_tri] = l2;
                ++T.n_tri;
            }
        }
    }
    // rows sorted by output order Mo; entries grouped by (Mo, triple)
    for (int l = 0; l <= LMAX; ++l) {
        for (int m = -l; m <= l; ++m) {
            const int Mo = l * l + l + m;
            T.mo_pstart[Mo] = T.np;
            for (int t = 0; t < T.n_tri; ++t) {
                if (T.tl[t] != l) continue;
                const int l1 = T.tl1[t], l2 = T.tl2[t];
                int lo = (-l1 > m - l2) ? -l1 : m - l2;
                int hi = (l1 < m + l2) ? l1 : m + l2;
                if (lo > hi) continue;
                T.pair_tri[T.np] = t;
                T.pair_kstart[T.np] = T.nnz;
                ++T.np;
                for (int m1 = lo; m1 <= hi; ++m1) {
                    const int m2 = m - m1;
                    T.M1[T.nnz] = l1 * l1 + l1 + m1;
                    T.M2[T.nnz] = l2 * l2 + l2 + m2;
                    ++T.nnz;
                }
            }
        }
    }
    T.mo_pstart[MOUT] = T.np;
    T.pair_kstart[T.np] = T.nnz;
    return T;
}

constexpr Tables TB = build_tables();
static_assert(TB.nnz == NNZ, "nnz mismatch vs reference _build_structure");
static_assert(TB.n_tri == NTRI, "n_tri mismatch vs reference _build_structure");
static_assert(TB.np == NPAIR, "pair count mismatch");

__global__ __launch_bounds__(256)
void wtp_kernel(const float* __restrict__ x1, const float* __restrict__ x2,
                const float* __restrict__ w, const float* __restrict__ cg,
                float* __restrict__ out, int B) {
    // per-triple weights staged in LDS: ws[t*CCH + c], 34*128*4 = 17408 B
    __shared__ float ws[NTRI * CCH];
    const int tid = threadIdx.x + 64 * threadIdx.y;     // 0..255
#pragma unroll
    for (int i = 0; i < NTRI * CCH / 256; ++i)          // 17 iters, exact
        ws[i * 256 + tid] = w[i * 256 + tid];
    __syncthreads();

    const int lane = threadIdx.x;                       // 0..63 == lane in wave
    const int c0 = lane * 2;                            // channel pair base
    const int b = blockIdx.x * 4 + threadIdx.y;         // batch
    if (b >= B) return;

    // cg staged across the wave's lanes: vcg[j] lane L holds cg[j*64+L].
    float vcg[NCGV];
#pragma unroll
    for (int j = 0; j < NCGV; ++j) {
        const int idx = j * 64 + lane;
        vcg[j] = (idx < NNZ) ? cg[idx] : 0.f;
    }

    const size_t base = (size_t)b * (MOUT * CCH) + c0;
    const f2* x1b = (const f2*)(x1 + base);
    const f2* x2b = (const f2*)(x2 + base);

    // x1/x2 rows for this (b, c0..c0+1) into registers:
    // dwordx2 per lane, 64 lanes x 8B = 512B contiguous per instruction
    f2 x1r[MOUT], x2r[MOUT];
#pragma unroll
    for (int m = 0; m < MOUT; ++m) {
        x1r[m] = x1b[m * (CCH / 2)];
        x2r[m] = x2b[m * (CCH / 2)];
    }

    const float* wsc = ws + c0;   // ds_read_b64, conflict-free (see header)
    f2* outb = (f2*)(out + base);
#pragma unroll
    for (int mo = 0; mo < MOUT; ++mo) {
        f2 acc = {0.f, 0.f};
#pragma unroll
        for (int p = TB.mo_pstart[mo]; p < TB.mo_pstart[mo + 1]; ++p) {
            f2 inner = {0.f, 0.f};
#pragma unroll
            for (int k = TB.pair_kstart[p]; k < TB.pair_kstart[p + 1]; ++k) {
                // wave-uniform cg[k]: v_readlane_b32 (VALU, const lane) -> SGPR,
                // shared by BOTH channels' FMAs
                const float cgk = __int_as_float(
                    __builtin_amdgcn_readlane(__float_as_int(vcg[k >> 6]), k & 63));
                inner += (x1r[TB.M1[k]] * x2r[TB.M2[k]]) * cgk;
            }
            const f2 wv = *(const f2*)(wsc + TB.pair_tri[p] * CCH);
            acc += wv * inner;
        }
        outb[mo * (CCH / 2)] = acc;
    }
}

extern "C" void kernel_launch(void* const* d_in, const int* in_sizes, int n_in,
                              void* d_out, int out_size, void* d_ws, size_t ws_size,
                              hipStream_t stream) {
    const float* x1 = (const float*)d_in[0];
    const float* x2 = (const float*)d_in[1];
    const float* w  = (const float*)d_in[2];
    const float* cg = (const float*)d_in[3];
    float* out = (float*)d_out;

    const int B = in_sizes[0] / (MOUT * CCH);   // 2048

    dim3 block(64, 4, 1);                       // 256 threads: lane = channel pair
    dim3 grid((B + 3) / 4, 1, 1);
    wtp_kernel<<<grid, block, 0, stream>>>(x1, x2, w, cg, out, B);
}